// Round 8
// baseline (108.763 us; speedup 1.0000x reference)
//
#include <hip/hip_runtime.h>
#include <stdint.h>

#define NROWS 8192
#define DIM 128
#define NCLASS 512
#define MARGIN 0.5f

typedef short short8 __attribute__((ext_vector_type(8)));   // 8 bf16 (4 VGPRs)
typedef float f32x4 __attribute__((ext_vector_type(4)));
typedef int   int4v __attribute__((ext_vector_type(4)));

static __device__ __forceinline__ unsigned short f2bf(float f) {
    union { float f; unsigned u; } x; x.f = f;
    unsigned u = x.u;
    return (unsigned short)((u + 0x7FFFu + ((u >> 16) & 1u)) >> 16);  // RNE
}
static __device__ __forceinline__ unsigned fbits(float f) {
    union { float f; unsigned u; } x; x.f = f; return x.u;
}

// ---------------------------------------------------------------------------
// hist: single block; LDS histogram of the 512 labels.
// ---------------------------------------------------------------------------
__global__ __launch_bounds__(1024) void hist(const int* __restrict__ labels,
                                             unsigned* __restrict__ bins) {
    __shared__ unsigned h[NCLASS];
    const int t = threadIdx.x;
    if (t < NCLASS) h[t] = 0u;
    __syncthreads();
#pragma unroll
    for (int k = 0; k < 8; ++k) atomicAdd(&h[labels[t + k * 1024]], 1u);
    __syncthreads();
    if (t < NCLASS) bins[t] = h[t];
}

// ---------------------------------------------------------------------------
// scan: single block; exclusive prefix of bins -> binstart; init cursor, out.
// ---------------------------------------------------------------------------
__global__ __launch_bounds__(512) void scan(const unsigned* __restrict__ bins,
                                            unsigned* __restrict__ binstart,
                                            unsigned* __restrict__ cursor,
                                            float* __restrict__ out) {
    __shared__ unsigned s[NCLASS];
    const int t = threadIdx.x;
    const unsigned v = bins[t];
    s[t] = v;
    __syncthreads();
    for (int off = 1; off < NCLASS; off <<= 1) {
        const unsigned x = (t >= off) ? s[t - off] : 0u;
        __syncthreads();
        s[t] += x;
        __syncthreads();
    }
    const unsigned excl = s[t] - v;
    binstart[t] = excl;
    cursor[t] = excl;
    if (t == 0) out[0] = 0.0f;
}

// ---------------------------------------------------------------------------
// scatterk: rank each row within its label bin -> perm (sorted -> original).
// ---------------------------------------------------------------------------
__global__ __launch_bounds__(256) void scatterk(const int* __restrict__ labels,
                                                unsigned* __restrict__ cursor,
                                                int* __restrict__ perm) {
    const int i = blockIdx.x * 256 + threadIdx.x;
    const unsigned p = atomicAdd(&cursor[labels[i]], 1u);
    perm[p] = i;
}

// ---------------------------------------------------------------------------
// build: for each sorted row p (one wave), gather original row perm[p],
// write fragment-ordered bf16 matrix (same layout as round 7, verified):
//   dst = efrag + (p>>4)*4096 + (d>>4)*1024 + (((d>>2)&3)*16 + (p&15))*16 + (d&3)*4
// plus cs[p]=sq+512, pos/neg init, run bounds rA/rB, sorted labels slab.
// ---------------------------------------------------------------------------
__global__ __launch_bounds__(256) void build(const float* __restrict__ emb,
                                             const int* __restrict__ labels,
                                             const int* __restrict__ perm,
                                             const unsigned* __restrict__ bins,
                                             const unsigned* __restrict__ binstart,
                                             char* __restrict__ efrag,
                                             float* __restrict__ cs,
                                             unsigned* __restrict__ pos,
                                             unsigned* __restrict__ neg,
                                             unsigned* __restrict__ rA,
                                             unsigned* __restrict__ rB,
                                             int* __restrict__ slab) {
    const int d = threadIdx.x & 63;
    const int p = blockIdx.x * 4 + (threadIdx.x >> 6);
    const int src = perm[p];
    const float2 v = reinterpret_cast<const float2*>(emb + (size_t)src * DIM)[d];
    float sq = v.x * v.x + v.y * v.y;
#pragma unroll
    for (int m = 1; m < 64; m <<= 1) sq += __shfl_xor(sq, m, 64);
    const unsigned pack = ((unsigned)f2bf(v.y) << 16) | (unsigned)f2bf(v.x);
    char* dst = efrag + (size_t)(p >> 4) * 4096 + (d >> 4) * 1024
              + ((((d >> 2) & 3) * 16 + (p & 15)) * 16) + (d & 3) * 4;
    *reinterpret_cast<unsigned*>(dst) = pack;
    const int lab = labels[src];
    if (d == 0) cs[p] = sq + 512.0f;
    if (d == 1) pos[p] = 0u;
    if (d == 2) neg[p] = 0xFFFFFFFFu;
    if (d == 3) rA[p] = binstart[lab];
    if (d == 4) rB[p] = binstart[lab] + bins[lab];
    if (d == 5) slab[p] = lab;
}

// ---------------------------------------------------------------------------
// mine_fast: Gram-GEMM + hardest-NEGATIVE mining on label-disjoint chunks.
// Grid 32 i-blocks x 32 j-chunks; block skips chunks overlapping the label
// window of its i-range (those are covered exactly by mine_slow).
// No label tests, no pos path: per element = and_or + min tree (~2.5 VALU).
// Score s = dot - c_j/2 < 0;  hardest negative = min d2 -> MIN u32 bits.
// Candidate = (s_bits & ~8191) | j'.  Publish atomicMin(neg[i']).
// ---------------------------------------------------------------------------
__global__ __launch_bounds__(256, 4) void mine_fast(const char* __restrict__ efrag,
                                                    const float* __restrict__ cs,
                                                    const unsigned* __restrict__ rA,
                                                    const unsigned* __restrict__ rB,
                                                    unsigned* __restrict__ neg) {
    const int iblk = blockIdx.x & 31;
    const int cblk = blockIdx.x >> 5;
    // slow-chunk window for this i-block (sorted rows iblk*256 .. +255)
    const unsigned wlo = rA[iblk * 256];
    const unsigned whi = rB[iblk * 256 + 255];
    const int cba = (int)(wlo >> 8), cbb = (int)((whi - 1u) >> 8);
    if (cblk >= cba && cblk <= cbb) return;   // handled by mine_slow

    const int tid  = threadIdx.x;
    const int wave = tid >> 6;
    const int lane = tid & 63;
    const int lhi  = lane >> 4;
    const int ibase = iblk * 256 + wave * 64;

    short8 bfrag[4][4];
#pragma unroll
    for (int it = 0; it < 4; ++it) {
        const char* bt = efrag + (size_t)((ibase >> 4) + it) * 4096 + lane * 16;
#pragma unroll
        for (int ks = 0; ks < 4; ++ks)
            bfrag[it][ks] = *reinterpret_cast<const short8*>(bt + ks * 1024);
    }

    unsigned bn[4] = {0xFFFFFFFFu, 0xFFFFFFFFu, 0xFFFFFFFFu, 0xFFFFFFFFu};
    const int jc = cblk * 256;
    const char* aj = efrag + (size_t)(cblk * 16) * 4096 + lane * 16;

#pragma unroll 2
    for (int jt = 0; jt < 16; ++jt) {
        const int jb = jc + jt * 16;
        const f32x4 cinit = *reinterpret_cast<const f32x4*>(cs + jb + lhi * 4) * -0.5f;
        const char* at = aj + (size_t)jt * 4096;

        const short8 af0 = *reinterpret_cast<const short8*>(at);
        const short8 af1 = *reinterpret_cast<const short8*>(at + 1024);
        f32x4 acc[4];
#pragma unroll
        for (int it = 0; it < 4; ++it)
            acc[it] = __builtin_amdgcn_mfma_f32_16x16x32_bf16(af0, bfrag[it][0], cinit, 0, 0, 0);
#pragma unroll
        for (int it = 0; it < 4; ++it)
            acc[it] = __builtin_amdgcn_mfma_f32_16x16x32_bf16(af1, bfrag[it][1], acc[it], 0, 0, 0);
        const short8 af2 = *reinterpret_cast<const short8*>(at + 2048);
        const short8 af3 = *reinterpret_cast<const short8*>(at + 3072);
#pragma unroll
        for (int it = 0; it < 4; ++it)
            acc[it] = __builtin_amdgcn_mfma_f32_16x16x32_bf16(af2, bfrag[it][2], acc[it], 0, 0, 0);
#pragma unroll
        for (int it = 0; it < 4; ++it)
            acc[it] = __builtin_amdgcn_mfma_f32_16x16x32_bf16(af3, bfrag[it][3], acc[it], 0, 0, 0);

        const unsigned jv = (unsigned)(jb + lhi * 4);
#pragma unroll
        for (int it = 0; it < 4; ++it) {
            const unsigned c0 = (fbits(acc[it][0]) & 0xFFFFE000u) | jv;
            const unsigned c1 = (fbits(acc[it][1]) & 0xFFFFE000u) | (jv + 1u);
            const unsigned c2 = (fbits(acc[it][2]) & 0xFFFFE000u) | (jv + 2u);
            const unsigned c3 = (fbits(acc[it][3]) & 0xFFFFE000u) | (jv + 3u);
            const unsigned m0 = c0 < c1 ? c0 : c1;
            const unsigned m1 = c2 < c3 ? c2 : c3;
            const unsigned m  = m0 < m1 ? m0 : m1;
            bn[it] = bn[it] < m ? bn[it] : m;
        }
    }

#pragma unroll
    for (int it = 0; it < 4; ++it) {
        unsigned o;
        o = (unsigned)__shfl_xor((int)bn[it], 16, 64); bn[it] = bn[it] < o ? bn[it] : o;
        o = (unsigned)__shfl_xor((int)bn[it], 32, 64); bn[it] = bn[it] < o ? bn[it] : o;
        if (lane < 16) atomicMin(&neg[ibase + it * 16 + lane], bn[it]);
    }
}

// ---------------------------------------------------------------------------
// mine_slow: full label-aware path (pos + neg) over ONLY the <=3 window
// chunks per i-block. Grid 32 x 3; duplicate chunks are idempotent.
// ---------------------------------------------------------------------------
__global__ __launch_bounds__(256, 4) void mine_slow(const char* __restrict__ efrag,
                                                    const float* __restrict__ cs,
                                                    const int* __restrict__ slab,
                                                    const unsigned* __restrict__ rA,
                                                    const unsigned* __restrict__ rB,
                                                    unsigned* __restrict__ pos,
                                                    unsigned* __restrict__ neg) {
    const int iblk = blockIdx.x;
    const unsigned wlo = rA[iblk * 256];
    const unsigned whi = rB[iblk * 256 + 255];
    const int cba = (int)(wlo >> 8), cbb = (int)((whi - 1u) >> 8);
    int cblk = cba + (int)blockIdx.y;
    if (cblk > cbb) cblk = cbb;               // clamp; duplicates idempotent

    const int tid  = threadIdx.x;
    const int wave = tid >> 6;
    const int lane = tid & 63;
    const int l15  = lane & 15;
    const int lhi  = lane >> 4;
    const int ibase = iblk * 256 + wave * 64;

    short8 bfrag[4][4];
    int labi[4];
#pragma unroll
    for (int it = 0; it < 4; ++it) {
        const char* bt = efrag + (size_t)((ibase >> 4) + it) * 4096 + lane * 16;
#pragma unroll
        for (int ks = 0; ks < 4; ++ks)
            bfrag[it][ks] = *reinterpret_cast<const short8*>(bt + ks * 1024);
        labi[it] = slab[ibase + it * 16 + l15];
    }

    unsigned bp[4] = {0u, 0u, 0u, 0u};
    unsigned bn[4] = {0xFFFFFFFFu, 0xFFFFFFFFu, 0xFFFFFFFFu, 0xFFFFFFFFu};
    const int jc = cblk * 256;
    const char* aj = efrag + (size_t)(cblk * 16) * 4096 + lane * 16;

#pragma unroll 2
    for (int jt = 0; jt < 16; ++jt) {
        const int jb = jc + jt * 16;
        const int4v labj = *reinterpret_cast<const int4v*>(slab + jb + lhi * 4);
        const f32x4 cinit = *reinterpret_cast<const f32x4*>(cs + jb + lhi * 4) * -0.5f;
        const char* at = aj + (size_t)jt * 4096;

        const short8 af0 = *reinterpret_cast<const short8*>(at);
        const short8 af1 = *reinterpret_cast<const short8*>(at + 1024);
        f32x4 acc[4];
#pragma unroll
        for (int it = 0; it < 4; ++it)
            acc[it] = __builtin_amdgcn_mfma_f32_16x16x32_bf16(af0, bfrag[it][0], cinit, 0, 0, 0);
#pragma unroll
        for (int it = 0; it < 4; ++it)
            acc[it] = __builtin_amdgcn_mfma_f32_16x16x32_bf16(af1, bfrag[it][1], acc[it], 0, 0, 0);
        const short8 af2 = *reinterpret_cast<const short8*>(at + 2048);
        const short8 af3 = *reinterpret_cast<const short8*>(at + 3072);
#pragma unroll
        for (int it = 0; it < 4; ++it)
            acc[it] = __builtin_amdgcn_mfma_f32_16x16x32_bf16(af2, bfrag[it][2], acc[it], 0, 0, 0);
#pragma unroll
        for (int it = 0; it < 4; ++it)
            acc[it] = __builtin_amdgcn_mfma_f32_16x16x32_bf16(af3, bfrag[it][3], acc[it], 0, 0, 0);

        const int jv = jb + lhi * 4;
#pragma unroll
        for (int it = 0; it < 4; ++it) {
#pragma unroll
            for (int r = 0; r < 4; ++r) {
                const unsigned cand = (fbits(acc[it][r]) & 0xFFFFE000u) | (unsigned)(jv + r);
                const bool eq = (labj[r] == labi[it]);
                const unsigned psel = eq ? cand : 0u;
                const unsigned nsel = eq ? 0xFFFFFFFFu : cand;
                bp[it] = bp[it] > psel ? bp[it] : psel;
                bn[it] = bn[it] < nsel ? bn[it] : nsel;
            }
        }
    }

#pragma unroll
    for (int it = 0; it < 4; ++it) {
        unsigned o;
        o = (unsigned)__shfl_xor((int)bp[it], 16, 64); bp[it] = bp[it] > o ? bp[it] : o;
        o = (unsigned)__shfl_xor((int)bp[it], 32, 64); bp[it] = bp[it] > o ? bp[it] : o;
        o = (unsigned)__shfl_xor((int)bn[it], 16, 64); bn[it] = bn[it] < o ? bn[it] : o;
        o = (unsigned)__shfl_xor((int)bn[it], 32, 64); bn[it] = bn[it] < o ? bn[it] : o;
        if (lane < 16) {
            const int i = ibase + it * 16 + lane;
            atomicMax(&pos[i], bp[it]);
            atomicMin(&neg[i], bn[it]);
        }
    }
}

// ---------------------------------------------------------------------------
// lossk: one sorted row per wave; map indices back through perm, exact f32
// ap/an, butterfly sum, per-block partial into bsum.
// ---------------------------------------------------------------------------
__global__ __launch_bounds__(256) void lossk(const float* __restrict__ emb,
                                             const int* __restrict__ perm,
                                             const unsigned* __restrict__ pos,
                                             const unsigned* __restrict__ neg,
                                             float* __restrict__ bsum) {
    __shared__ float wsum[4];
    const int tid = threadIdx.x, lane = tid & 63, wave = tid >> 6;
    const int i = blockIdx.x * 4 + wave;          // sorted row 0..8191
    const int pi = perm[i];
    const int jp = perm[pos[i] & 8191u];
    const int jn = perm[neg[i] & 8191u];
    const float2 a = reinterpret_cast<const float2*>(emb + (size_t)pi * DIM)[lane];
    const float2 b = reinterpret_cast<const float2*>(emb + (size_t)jp * DIM)[lane];
    const float2 c = reinterpret_cast<const float2*>(emb + (size_t)jn * DIM)[lane];
    float dx = a.x - b.x, dy = a.y - b.y;
    const float ap = dx * dx + dy * dy;
    dx = a.x - c.x; dy = a.y - c.y;
    const float an = dx * dx + dy * dy;
    float s = ap - an;
#pragma unroll
    for (int m = 1; m < 64; m <<= 1) s += __shfl_xor(s, m, 64);
    if (lane == 0) wsum[wave] = fmaxf(s + MARGIN, 0.f);
    __syncthreads();
    if (tid == 0) bsum[blockIdx.x] = wsum[0] + wsum[1] + wsum[2] + wsum[3];
}

// ---------------------------------------------------------------------------
// fin: reduce 2048 block sums -> mean. One block.
// ---------------------------------------------------------------------------
__global__ __launch_bounds__(256) void fin(const float* __restrict__ bsum,
                                           float* __restrict__ out) {
    __shared__ float wsum[4];
    const int tid = threadIdx.x, lane = tid & 63, wave = tid >> 6;
    float s = 0.f;
#pragma unroll
    for (int k = 0; k < 8; ++k) s += bsum[tid + k * 256];
#pragma unroll
    for (int m = 1; m < 64; m <<= 1) s += __shfl_xor(s, m, 64);
    if (lane == 0) wsum[wave] = s;
    __syncthreads();
    if (tid == 0) out[0] = (wsum[0] + wsum[1] + wsum[2] + wsum[3]) * (1.0f / (float)NROWS);
}

// ---------------------------------------------------------------------------
extern "C" void kernel_launch(void* const* d_in, const int* in_sizes, int n_in,
                              void* d_out, int out_size, void* d_ws, size_t ws_size,
                              hipStream_t stream) {
    const float* emb   = (const float*)d_in[0];
    const int* labels  = (const int*)d_in[1];
    float* out = (float*)d_out;
    char* ws = (char*)d_ws;

    char*     efrag    = ws;                                    // 2 MB
    float*    cs       = (float*)   (ws + 2097152);             // 32 KB
    unsigned* pos      = (unsigned*)(ws + 2129920);             // 32 KB
    unsigned* neg      = (unsigned*)(ws + 2162688);             // 32 KB
    float*    bsum     = (float*)   (ws + 2195456);             // 8 KB
    unsigned* bins     = (unsigned*)(ws + 2203648);             // 2 KB
    unsigned* binstart = (unsigned*)(ws + 2205696);             // 2 KB
    unsigned* cursor   = (unsigned*)(ws + 2207744);             // 2 KB
    int*      perm     = (int*)     (ws + 2209792);             // 32 KB
    unsigned* rA       = (unsigned*)(ws + 2242560);             // 32 KB
    unsigned* rB       = (unsigned*)(ws + 2275328);             // 32 KB
    int*      slab     = (int*)     (ws + 2308096);             // 32 KB

    hist    <<<1, 1024, 0, stream>>>(labels, bins);
    scan    <<<1, 512, 0, stream>>>(bins, binstart, cursor, out);
    scatterk<<<32, 256, 0, stream>>>(labels, cursor, perm);
    build   <<<2048, 256, 0, stream>>>(emb, labels, perm, bins, binstart,
                                       efrag, cs, pos, neg, rA, rB, slab);
    mine_fast<<<1024, 256, 0, stream>>>(efrag, cs, rA, rB, neg);
    mine_slow<<<dim3(32, 3), 256, 0, stream>>>(efrag, cs, slab, rA, rB, pos, neg);
    lossk   <<<2048, 256, 0, stream>>>(emb, perm, pos, neg, bsum);
    fin     <<<1, 256, 0, stream>>>(bsum, out);
}